// Round 1
// baseline (301.326 us; speedup 1.0000x reference)
//
#include <hip/hip_runtime.h>
#include <hip/hip_bf16.h>

// Problem constants: B=4, N=4096, DIM=1024; qkva = [B*N, 3*DIM]
#define SEQ_N 4096
#define BATCH 4
#define DIM 1024
#define M_ROWS (BATCH * SEQ_N)      // 16384
#define NCOLS (3 * DIM)             // 3072
#define KDIM DIM                    // 1024
#define CHUNK_L 64
#define NCHUNK (SEQ_N / CHUNK_L)    // 64
#define NCHANNEL (BATCH * DIM)      // 4096

using short8 = __attribute__((ext_vector_type(8))) short;
using f32x4  = __attribute__((ext_vector_type(4))) float;

static __device__ __forceinline__ unsigned short f2bf(float f) {
    union { float f; unsigned u; } v; v.f = f;
    unsigned r = v.u + 0x7fffu + ((v.u >> 16) & 1u);   // round-to-nearest-even
    return (unsigned short)(r >> 16);
}
static __device__ __forceinline__ float bf2f(unsigned short s) {
    union { unsigned u; float f; } v; v.u = ((unsigned)s) << 16;
    return v.f;
}

// ---------------- w fp32 -> bf16 ----------------
__global__ __launch_bounds__(256) void wconv_kernel(const float* __restrict__ in,
                                                    unsigned short* __restrict__ out,
                                                    int n4) {
    int i = blockIdx.x * 256 + threadIdx.x;
    if (i < n4) {
        float4 v = reinterpret_cast<const float4*>(in)[i];
        ushort4 o;
        o.x = f2bf(v.x); o.y = f2bf(v.y); o.z = f2bf(v.z); o.w = f2bf(v.w);
        reinterpret_cast<ushort4*>(out)[i] = o;
    }
}

// ---------------- RMSNorm (per row of 1024) -> bf16 ----------------
__global__ __launch_bounds__(256) void rmsnorm_kernel(const float* __restrict__ x,
                                                      const float* __restrict__ gamma,
                                                      unsigned short* __restrict__ h) {
    const int row = blockIdx.x;
    const int tid = threadIdx.x;
    const float4 v = reinterpret_cast<const float4*>(x + (size_t)row * DIM)[tid];
    float ss = v.x * v.x + v.y * v.y + v.z * v.z + v.w * v.w;
#pragma unroll
    for (int off = 32; off >= 1; off >>= 1) ss += __shfl_xor(ss, off, 64);
    __shared__ float red[4];
    if ((tid & 63) == 0) red[tid >> 6] = ss;
    __syncthreads();
    const float tot = red[0] + red[1] + red[2] + red[3];
    const float scale = 32.0f / fmaxf(sqrtf(tot), 1e-12f);   // sqrt(1024)=32
    const float4 g = reinterpret_cast<const float4*>(gamma)[tid];
    ushort4 o;
    o.x = f2bf(v.x * scale * g.x);
    o.y = f2bf(v.y * scale * g.y);
    o.z = f2bf(v.z * scale * g.z);
    o.w = f2bf(v.w * scale * g.w);
    reinterpret_cast<ushort4*>(h + (size_t)row * DIM)[tid] = o;
}

// ---------------- GEMM: C[m,e] = sum_k A[m,k] * B[e,k], bf16 in, bf16 out ----
// m97-style: 128x128 tile, BK=32, 4 waves (2x2 of 64x64), 16x16x32 bf16 MFMA,
// global_load_lds width-16 staging (LDS layout contiguous in tid order).
__global__ __launch_bounds__(256) void gemm_bt_kernel(const unsigned short* __restrict__ A,
                                                      const unsigned short* __restrict__ B,
                                                      unsigned short* __restrict__ C) {
    __shared__ __align__(16) unsigned short sA[128 * 32];
    __shared__ __align__(16) unsigned short sB[128 * 32];

    const int tid  = threadIdx.x;
    const int lane = tid & 63;
    const int wave = tid >> 6;
    const int row0 = blockIdx.y * 128;
    const int col0 = blockIdx.x * 128;
    const int wm = (wave >> 1) * 64;
    const int wn = (wave & 1) * 64;
    const int fr = lane & 15;   // frag row/col within 16x16
    const int kq = lane >> 4;   // k-quad (which 8 of K=32)

    const unsigned short* agp = A + (size_t)(row0 + (tid >> 2)) * KDIM + (tid & 3) * 8;
    const unsigned short* bgp = B + (size_t)(col0 + (tid >> 2)) * KDIM + (tid & 3) * 8;

    f32x4 acc[4][4] = {};

    for (int k0 = 0; k0 < KDIM; k0 += 32) {
        __builtin_amdgcn_global_load_lds(
            (const __attribute__((address_space(1))) void*)(agp),
            (__attribute__((address_space(3))) void*)(&sA[tid * 8]), 16, 0, 0);
        __builtin_amdgcn_global_load_lds(
            (const __attribute__((address_space(1))) void*)(agp + 64 * KDIM),
            (__attribute__((address_space(3))) void*)(&sA[2048 + tid * 8]), 16, 0, 0);
        __builtin_amdgcn_global_load_lds(
            (const __attribute__((address_space(1))) void*)(bgp),
            (__attribute__((address_space(3))) void*)(&sB[tid * 8]), 16, 0, 0);
        __builtin_amdgcn_global_load_lds(
            (const __attribute__((address_space(1))) void*)(bgp + 64 * KDIM),
            (__attribute__((address_space(3))) void*)(&sB[2048 + tid * 8]), 16, 0, 0);
        agp += 32; bgp += 32;
        __syncthreads();

        short8 af[4], bf[4];
#pragma unroll
        for (int i = 0; i < 4; ++i)
            af[i] = *reinterpret_cast<const short8*>(&sA[(wm + i * 16 + fr) * 32 + kq * 8]);
#pragma unroll
        for (int j = 0; j < 4; ++j)
            bf[j] = *reinterpret_cast<const short8*>(&sB[(wn + j * 16 + fr) * 32 + kq * 8]);
#pragma unroll
        for (int i = 0; i < 4; ++i)
#pragma unroll
            for (int j = 0; j < 4; ++j)
                acc[i][j] = __builtin_amdgcn_mfma_f32_16x16x32_bf16(af[i], bf[j], acc[i][j], 0, 0, 0);
        __syncthreads();
    }

    // epilogue: C/D layout col=lane&15, row=(lane>>4)*4+reg
#pragma unroll
    for (int i = 0; i < 4; ++i) {
#pragma unroll
        for (int j = 0; j < 4; ++j) {
#pragma unroll
            for (int r = 0; r < 4; ++r) {
                int row = row0 + wm + i * 16 + kq * 4 + r;
                int col = col0 + wn + j * 16 + fr;
                C[(size_t)row * NCOLS + col] = f2bf(acc[i][j][r]);
            }
        }
    }
}

// ---------------- Scan phase 1: per-chunk aggregates (A = prod a, Y = local state)
__global__ __launch_bounds__(256) void chunk_agg_kernel(const unsigned short* __restrict__ qkva,
                                                        float* __restrict__ Aagg,
                                                        float* __restrict__ Yagg) {
    const int c = blockIdx.x, dt = blockIdx.y, b = blockIdx.z;
    const int d = dt * 256 + threadIdx.x;
    const unsigned short* base = qkva + ((size_t)b * SEQ_N + c * CHUNK_L) * NCOLS;
    float s = 0.f, A = 1.f;
    for (int n = 0; n < CHUNK_L; ++n) {
        float kv = bf2f(base[(size_t)n * NCOLS + DIM + d]);
        float av = bf2f(base[(size_t)n * NCOLS + 2 * DIM + d]);
        float a = 1.f / (1.f + __expf(-av));
        s = a * s + kv;
        A *= a;
    }
    const int idx = c * NCHANNEL + b * DIM + d;
    Aagg[idx] = A;
    Yagg[idx] = s;
}

// ---------------- Scan phase 2: sequential scan over chunk aggregates -> chunk entry state
__global__ __launch_bounds__(256) void agg_scan_kernel(const float* __restrict__ Aagg,
                                                       const float* __restrict__ Yagg,
                                                       float* __restrict__ Sin) {
    const int ch = blockIdx.x * 256 + threadIdx.x;   // 0..4095
    float s = 0.f;
    for (int c = 0; c < NCHUNK; ++c) {
        Sin[c * NCHANNEL + ch] = s;
        s = Aagg[c * NCHANNEL + ch] * s + Yagg[c * NCHANNEL + ch];
    }
}

// ---------------- Scan phase 3: rescan chunk with correct entry state, out = q*y
__global__ __launch_bounds__(256) void apply_kernel(const unsigned short* __restrict__ qkva,
                                                    const float* __restrict__ Sin,
                                                    float* __restrict__ out) {
    const int c = blockIdx.x, dt = blockIdx.y, b = blockIdx.z;
    const int d = dt * 256 + threadIdx.x;
    const unsigned short* base = qkva + ((size_t)b * SEQ_N + c * CHUNK_L) * NCOLS;
    float* obase = out + ((size_t)b * SEQ_N + c * CHUNK_L) * DIM;
    float s = Sin[c * NCHANNEL + b * DIM + d];
    for (int n = 0; n < CHUNK_L; ++n) {
        float kv = bf2f(base[(size_t)n * NCOLS + DIM + d]);
        float av = bf2f(base[(size_t)n * NCOLS + 2 * DIM + d]);
        float a = 1.f / (1.f + __expf(-av));
        s = a * s + kv;
        float q = bf2f(base[(size_t)n * NCOLS + d]);
        obase[(size_t)n * DIM + d] = q * s;
    }
}

extern "C" void kernel_launch(void* const* d_in, const int* in_sizes, int n_in,
                              void* d_out, int out_size, void* d_ws, size_t ws_size,
                              hipStream_t stream) {
    const float* x     = (const float*)d_in[0];   // [4,4096,1024]
    const float* w     = (const float*)d_in[1];   // [3072,1024]
    const float* gamma = (const float*)d_in[2];   // [1024]
    float* out = (float*)d_out;                   // [4,4096,1024]

    char* ws = (char*)d_ws;
    // workspace layout (bytes):
    unsigned short* wb   = (unsigned short*)(ws);                         // 3072*1024*2   = 6,291,456
    unsigned short* h    = (unsigned short*)(ws + 6291456);               // 16384*1024*2  = 33,554,432
    unsigned short* qkva = (unsigned short*)(ws + 39845888);              // 16384*3072*2  = 100,663,296
    float* Aagg = (float*)(ws + 140509184);                               // 64*4096*4     = 1,048,576
    float* Yagg = (float*)(ws + 141557760);                               // 1,048,576
    float* Sin  = (float*)(ws + 142606336);                               // 1,048,576
    // total: 143,654,912 bytes

    wconv_kernel<<<(NCOLS * KDIM / 4 + 255) / 256, 256, 0, stream>>>(w, wb, NCOLS * KDIM / 4);
    rmsnorm_kernel<<<M_ROWS, 256, 0, stream>>>(x, gamma, h);
    gemm_bt_kernel<<<dim3(NCOLS / 128, M_ROWS / 128), 256, 0, stream>>>(h, wb, qkva);
    chunk_agg_kernel<<<dim3(NCHUNK, DIM / 256, BATCH), 256, 0, stream>>>(qkva, Aagg, Yagg);
    agg_scan_kernel<<<NCHANNEL / 256, 256, 0, stream>>>(Aagg, Yagg, Sin);
    apply_kernel<<<dim3(NCHUNK, DIM / 256, BATCH), 256, 0, stream>>>(qkva, Sin, out);
}